// Round 11
// baseline (129.162 us; speedup 1.0000x reference)
//
#include <hip/hip_runtime.h>

typedef unsigned short u16;
typedef unsigned int u32;

#define H_ 12
#define DH_ 64
#define D_ 768
#define S_ 1024
#define B_ 8
#define M_TOT 8192   // B_*S_
#define LOG2E 1.44269504089f

using f32x4  = __attribute__((ext_vector_type(4))) float;
using bf16x8 = __attribute__((ext_vector_type(8))) short;

__device__ inline u16 f2bf(float f) {
  union { float f; u32 u; } v; v.f = f;
  u32 r = v.u + 0x7FFFu + ((v.u >> 16) & 1u);
  return (u16)(r >> 16);
}

__device__ inline float bf2f(u16 b) {
  union { u32 u; float f; } v; v.u = ((u32)b) << 16;
  return v.f;
}

__device__ inline void gload_lds16(const u16* g, u16* l) {
  __builtin_amdgcn_global_load_lds((const __attribute__((address_space(1))) void*)g,
                                   (__attribute__((address_space(3))) void*)l, 16, 0, 0);
}

// ---------------- conversion: f32 -> bf16 (vectorized) ----------------
__global__ void convert_all(const float* __restrict__ X,
                            const float* __restrict__ Wq, const float* __restrict__ Wk,
                            const float* __restrict__ Wv, const float* __restrict__ Wd,
                            u16* __restrict__ Xb, u16* __restrict__ Wqkv, u16* __restrict__ Wdb) {
  int stride = gridDim.x * blockDim.x;
  int tid = blockIdx.x * blockDim.x + threadIdx.x;
  const int NX4 = M_TOT * D_ / 4;
  const int NW4 = D_ * D_ / 4;
  const int NW = D_ * D_;
  for (int i = tid; i < NX4; i += stride) {
    float4 x = ((const float4*)X)[i];
    uint2 p;
    p.x = (u32)f2bf(x.x) | ((u32)f2bf(x.y) << 16);
    p.y = (u32)f2bf(x.z) | ((u32)f2bf(x.w) << 16);
    ((uint2*)Xb)[i] = p;
  }
  for (int i = tid; i < NW4; i += stride) {
    float4 q = ((const float4*)Wq)[i];
    float4 k = ((const float4*)Wk)[i];
    float4 v = ((const float4*)Wv)[i];
    float4 d = ((const float4*)Wd)[i];
    uint2 pq, pk, pv, pd;
    pq.x = (u32)f2bf(q.x) | ((u32)f2bf(q.y) << 16); pq.y = (u32)f2bf(q.z) | ((u32)f2bf(q.w) << 16);
    pk.x = (u32)f2bf(k.x) | ((u32)f2bf(k.y) << 16); pk.y = (u32)f2bf(k.z) | ((u32)f2bf(k.w) << 16);
    pv.x = (u32)f2bf(v.x) | ((u32)f2bf(v.y) << 16); pv.y = (u32)f2bf(v.z) | ((u32)f2bf(v.w) << 16);
    pd.x = (u32)f2bf(d.x) | ((u32)f2bf(d.y) << 16); pd.y = (u32)f2bf(d.z) | ((u32)f2bf(d.w) << 16);
    ((uint2*)Wqkv)[i]            = pq;
    ((uint2*)(Wqkv + NW))[i]     = pk;
    ((uint2*)(Wqkv + 2*NW))[i]   = pv;
    ((uint2*)Wdb)[i]             = pd;
  }
}

// ======================= GEMM 1: QKV projection =======================
#define NT_ 24   // 768/32

__global__ __launch_bounds__(256, 4) void gemm_qkv(
    const u16* __restrict__ A, const u16* __restrict__ Bw,
    const float* __restrict__ bq, const float* __restrict__ bk, const float* __restrict__ bv,
    u16* __restrict__ Q, u16* __restrict__ K, u16* __restrict__ Vt) {
  __shared__ u16 As[2 * 128 * 32];   // 16 KB
  __shared__ u16 Bs[2 * 128 * 32];   // 16 KB
  int tid = threadIdx.x, lane = tid & 63, wave = tid >> 6;
  int wg = blockIdx.x;
  int xcd = wg & 7, li = wg >> 3;          // li 0..143 = 8 m * 18 n
  int m0 = (xcd * 8 + (li & 7)) * 128;
  int n0 = (li >> 3) * 128;
  int wm = (wave >> 1) * 64, wn = (wave & 1) * 64;
  int fr = lane & 15, fg = lane >> 4;
  f32x4 acc[4][4] = {};

  int srow = tid >> 2;                          // 0..63
  int schunk = (lane & 3) ^ ((lane >> 3) & 3);  // pre-swizzled source chunk
  const u16* AgS = A  + (size_t)(m0 + srow) * D_ + schunk * 8;
  const u16* BgS = Bw + (size_t)(n0 + srow) * D_ + schunk * 8;
  u16* Abase = &As[wave * 512];
  u16* Bbase = &Bs[wave * 512];
  int ra = (fg ^ ((fr >> 1) & 3)) * 8;          // swizzled read chunk offset

  gload_lds16(AgS,            Abase);
  gload_lds16(AgS + 64 * D_,  Abase + 2048);
  gload_lds16(BgS,            Bbase);
  gload_lds16(BgS + 64 * D_,  Bbase + 2048);
  __syncthreads();

  for (int t = 0; t < NT_; ++t) {
    int cur = t & 1, nxt = cur ^ 1;
    if (t < NT_ - 1) {
      int k1 = (t + 1) * 32;
      gload_lds16(AgS + k1,           Abase + nxt * 4096);
      gload_lds16(AgS + 64 * D_ + k1, Abase + nxt * 4096 + 2048);
      gload_lds16(BgS + k1,           Bbase + nxt * 4096);
      gload_lds16(BgS + 64 * D_ + k1, Bbase + nxt * 4096 + 2048);
    }
    bf16x8 af[4], bf[4];
#pragma unroll
    for (int i = 0; i < 4; i++) {
      af[i] = *(const bf16x8*)&As[cur * 4096 + (wm + i * 16 + fr) * 32 + ra];
      bf[i] = *(const bf16x8*)&Bs[cur * 4096 + (wn + i * 16 + fr) * 32 + ra];
    }
    __builtin_amdgcn_s_setprio(1);
#pragma unroll
    for (int mi = 0; mi < 4; mi++)
#pragma unroll
      for (int ni = 0; ni < 4; ni++)
        acc[mi][ni] = __builtin_amdgcn_mfma_f32_16x16x32_bf16(af[mi], bf[ni], acc[mi][ni], 0, 0, 0);
    __builtin_amdgcn_s_setprio(0);
    __syncthreads();
  }

  int which = n0 / D_;
  int ncol0 = n0 % D_;
  const float* bias = (which == 0) ? bq : (which == 1) ? bk : bv;
  if (which == 2) {
#pragma unroll
    for (int mi = 0; mi < 4; mi++)
#pragma unroll
      for (int ni = 0; ni < 4; ni++) {
        int col = ncol0 + wn + ni*16 + fr;
        float bb = bias[col];
        int row = m0 + wm + mi*16 + fg*4;
        int bidx = row >> 10, s = row & 1023;
        int hh = col >> 6, dd = col & 63;
        u16 t0 = f2bf(acc[mi][ni][0] + bb);
        u16 t1 = f2bf(acc[mi][ni][1] + bb);
        u16 t2 = f2bf(acc[mi][ni][2] + bb);
        u16 t3 = f2bf(acc[mi][ni][3] + bb);
        uint2 pk2;
        pk2.x = (u32)t0 | ((u32)t1 << 16);
        pk2.y = (u32)t2 | ((u32)t3 << 16);
        *(uint2*)(Vt + ((size_t)((bidx * H_ + hh) * DH_ + dd)) * S_ + s) = pk2;
      }
  } else {
    u16* Out = (which == 0) ? Q : K;
    float scale = (which == 0) ? (0.125f * LOG2E) : 1.0f;
#pragma unroll
    for (int mi = 0; mi < 4; mi++)
#pragma unroll
      for (int ni = 0; ni < 4; ni++) {
        int col = ncol0 + wn + ni*16 + fr;
        float bb = bias[col];
#pragma unroll
        for (int r = 0; r < 4; r++) {
          int row = m0 + wm + mi*16 + fg*4 + r;
          Out[row * D_ + col] = f2bf((acc[mi][ni][r] + bb) * scale);
        }
      }
  }
}

// ============ GEMM 2: output projection + bias + residual (bf16 Tmp) =======
__global__ __launch_bounds__(256, 4) void gemm_out(
    const u16* __restrict__ A, const u16* __restrict__ Bw,
    const float* __restrict__ bd, const float* __restrict__ hidden,
    u16* __restrict__ Tmp) {
  __shared__ u16 As[2 * 64 * 32];    // 8 KB
  __shared__ u16 Bs[2 * 128 * 32];   // 16 KB
  int tid = threadIdx.x, lane = tid & 63, wave = tid >> 6;
  int wg = blockIdx.x;
  int xcd = wg & 7, li = wg >> 3;          // 0..95 = 16 m * 6 n
  int m0 = (xcd * 16 + (li & 15)) * 64;
  int n0 = (li >> 4) * 128;
  int wm = (wave >> 1) * 32, wn = (wave & 1) * 64;
  int fr = lane & 15, fg = lane >> 4;
  f32x4 acc[2][4] = {};

  int srow = tid >> 2;                          // 0..63
  int schunk = (lane & 3) ^ ((lane >> 3) & 3);
  const u16* AgS = A  + (size_t)(m0 + srow) * D_ + schunk * 8;
  const u16* BgS = Bw + (size_t)(n0 + srow) * D_ + schunk * 8;
  u16* Abase = &As[wave * 512];
  u16* Bbase = &Bs[wave * 512];
  int ra = (fg ^ ((fr >> 1) & 3)) * 8;

  gload_lds16(AgS,            Abase);
  gload_lds16(BgS,            Bbase);
  gload_lds16(BgS + 64 * D_,  Bbase + 2048);
  __syncthreads();

  for (int t = 0; t < NT_; ++t) {
    int cur = t & 1, nxt = cur ^ 1;
    if (t < NT_ - 1) {
      int k1 = (t + 1) * 32;
      gload_lds16(AgS + k1,           Abase + nxt * 2048);
      gload_lds16(BgS + k1,           Bbase + nxt * 4096);
      gload_lds16(BgS + 64 * D_ + k1, Bbase + nxt * 4096 + 2048);
    }
    bf16x8 af[2], bf[4];
#pragma unroll
    for (int i = 0; i < 2; i++)
      af[i] = *(const bf16x8*)&As[cur * 2048 + (wm + i * 16 + fr) * 32 + ra];
#pragma unroll
    for (int i = 0; i < 4; i++)
      bf[i] = *(const bf16x8*)&Bs[cur * 4096 + (wn + i * 16 + fr) * 32 + ra];
    __builtin_amdgcn_s_setprio(1);
#pragma unroll
    for (int mi = 0; mi < 2; mi++)
#pragma unroll
      for (int ni = 0; ni < 4; ni++)
        acc[mi][ni] = __builtin_amdgcn_mfma_f32_16x16x32_bf16(af[mi], bf[ni], acc[mi][ni], 0, 0, 0);
    __builtin_amdgcn_s_setprio(0);
    __syncthreads();
  }

#pragma unroll
  for (int mi = 0; mi < 2; mi++)
#pragma unroll
    for (int ni = 0; ni < 4; ni++) {
      int col = n0 + wn + ni*16 + fr;
      float bb = bd[col];
#pragma unroll
      for (int r = 0; r < 4; r++) {
        int row = m0 + wm + mi*16 + fg*4 + r;
        Tmp[row * D_ + col] = f2bf(acc[mi][ni][r] + bb + hidden[(size_t)row * D_ + col]);
      }
    }
}

// ---------------- Attention (swapped-QK^T, XOR-swizzled LDS, async dbuf) ---
// 1536 blocks (XCD-swizzled: 12 heads/XCD, 16 q-tiles of 64), 4 waves x
// 16 q-rows. One barrier per tile. LDS 40KB -> 4 blocks/CU. Mask pre-scaled
// by log2e staged once in LDS, enters as MFMA C-init.
__global__ __launch_bounds__(256) void attn_kernel(
    const u16* __restrict__ Q, const u16* __restrict__ K, const u16* __restrict__ Vt,
    const float* __restrict__ mask, u16* __restrict__ Ctx) {
  __shared__ u16 Ks[2][64 * 64];   // 16 KB
  __shared__ u16 Vs[2][64 * 64];   // 16 KB
  __shared__ u16 Ps[4][16 * 64];   //  8 KB (per-wave strip)
  __shared__ float Ms[S_];         //  4 KB
  int tid = threadIdx.x, lane = tid & 63, wave = tid >> 6;
  int i = blockIdx.x;
  int xcd = i & 7, slot = i >> 3;        // 0..191
  int bh = xcd * 12 + (slot >> 4);
  int qt = slot & 15;
  int b = bh / H_, h = bh % H_;
  int q0 = qt * 64 + wave * 16;
  int fr = lane & 15, fg = lane >> 4;

  { // stage mask row (pre-scaled by log2e), once
    float4 m4 = ((const float4*)(mask + b * S_))[tid];
    m4.x *= LOG2E; m4.y *= LOG2E; m4.z *= LOG2E; m4.w *= LOG2E;
    ((float4*)Ms)[tid] = m4;
  }

  const u16* Qrow = Q + (size_t)(b * S_ + q0 + fr) * D_ + h * DH_;
  bf16x8 qf0 = *(const bf16x8*)(Qrow + fg * 8);
  bf16x8 qf1 = *(const bf16x8*)(Qrow + 32 + fg * 8);

  // staging addresses (64 rows x 2 int4 per thread-quad)
  int srow = tid >> 2;
  int scc = (tid & 3) * 16;
  int sw = (srow & 7) << 3;
  int sidx0 = srow * 64 + (scc ^ sw);
  int sidx1 = srow * 64 + ((scc + 8) ^ sw);
  const u16* Kg0 = K  + (size_t)(b * S_ + srow) * D_ + h * DH_ + scc;
  const u16* Vg0 = Vt + (size_t)(bh * DH_ + srow) * S_ + scc;

  // fragment read offsets (swizzled)
  int frw = (fr & 7) << 3;
  int rc0 = (fg * 8) ^ frw;
  int rc1 = (32 + fg * 8) ^ frw;
  int pcw[4];
#pragma unroll
  for (int kb = 0; kb < 4; kb++) pcw[kb] = (kb * 16 + fg * 4) ^ frw;

  f32x4 acc[4] = {};
  float l_part = 0.f;

  // prologue: stage tile 0 into buf 0
  int4 kr0 = *(const int4*)Kg0;
  int4 kr1 = *(const int4*)(Kg0 + 8);
  int4 vr0 = *(const int4*)Vg0;
  int4 vr1 = *(const int4*)(Vg0 + 8);
  *(int4*)&Ks[0][sidx0] = kr0; *(int4*)&Ks[0][sidx1] = kr1;
  *(int4*)&Vs[0][sidx0] = vr0; *(int4*)&Vs[0][sidx1] = vr1;
  __syncthreads();

  u16* Pw = Ps[wave];

  for (int t = 0; t < 16; ++t) {
    int cur = t & 1;
    int kt = t * 64;
    if (t < 15) {  // issue next-tile loads early; latency hides under compute
      const u16* Kg = Kg0 + (size_t)(kt + 64) * D_;
      const u16* Vg = Vg0 + (kt + 64);
      kr0 = *(const int4*)Kg; kr1 = *(const int4*)(Kg + 8);
      vr0 = *(const int4*)Vg; vr1 = *(const int4*)(Vg + 8);
    }

#pragma unroll
    for (int kb = 0; kb < 4; kb++) {
      int r = kb * 16 + fr;
      bf16x8 kf0 = *(const bf16x8*)&Ks[cur][r * 64 + rc0];
      bf16x8 kf1 = *(const bf16x8*)&Ks[cur][r * 64 + rc1];
      float4 m4 = *(const float4*)&Ms[kt + kb*16 + fg*4];
      f32x4 sv; sv[0] = m4.x; sv[1] = m4.y; sv[2] = m4.z; sv[3] = m4.w;
      sv = __builtin_amdgcn_mfma_f32_16x16x32_bf16(kf0, qf0, sv, 0, 0, 0);
      sv = __builtin_amdgcn_mfma_f32_16x16x32_bf16(kf1, qf1, sv, 0, 0, 0);
      float p0 = __builtin_amdgcn_exp2f(sv[0]);
      float p1 = __builtin_amdgcn_exp2f(sv[1]);
      float p2 = __builtin_amdgcn_exp2f(sv[2]);
      float p3 = __builtin_amdgcn_exp2f(sv[3]);
      l_part += (p0 + p1) + (p2 + p3);
      u32 lo, hi;
      asm("v_cvt_pk_bf16_f32 %0, %1, %2" : "=v"(lo) : "v"(p0), "v"(p1));
      asm("v_cvt_pk_bf16_f32 %0, %1, %2" : "=v"(hi) : "v"(p2), "v"(p3));
      uint2 pk2; pk2.x = lo; pk2.y = hi;
      *(uint2*)&Pw[fr * 64 + pcw[kb]] = pk2;
    }
    bf16x8 pf0 = *(const bf16x8*)&Pw[fr * 64 + rc0];
    bf16x8 pf1 = *(const bf16x8*)&Pw[fr * 64 + rc1];

    __builtin_amdgcn_s_setprio(1);
#pragma unroll
    for (int ns = 0; ns < 4; ns++) {
      int r = ns * 16 + fr;
      bf16x8 vf0 = *(const bf16x8*)&Vs[cur][r * 64 + rc0];
      bf16x8 vf1 = *(const bf16x8*)&Vs[cur][r * 64 + rc1];
      acc[ns] = __builtin_amdgcn_mfma_f32_16x16x32_bf16(pf0, vf0, acc[ns], 0, 0, 0);
      acc[ns] = __builtin_amdgcn_mfma_f32_16x16x32_bf16(pf1, vf1, acc[ns], 0, 0, 0);
    }
    __builtin_amdgcn_s_setprio(0);

    if (t < 15) {  // write next tile into the other buffer; one barrier/tile
      int nxt = cur ^ 1;
      *(int4*)&Ks[nxt][sidx0] = kr0; *(int4*)&Ks[nxt][sidx1] = kr1;
      *(int4*)&Vs[nxt][sidx0] = vr0; *(int4*)&Vs[nxt][sidx1] = vr1;
      __syncthreads();
    }
  }

  l_part += __shfl_xor(l_part, 16);
  l_part += __shfl_xor(l_part, 32);
  float inv = 1.0f / l_part;
  float li[4];
#pragma unroll
  for (int r = 0; r < 4; r++)
    li[r] = __shfl(inv, fg*4 + r);   // redistribute to C-write rows

  u16* Crow = Ctx + (size_t)(b * S_ + q0) * D_ + h * DH_;
#pragma unroll
  for (int ns = 0; ns < 4; ns++)
#pragma unroll
    for (int r = 0; r < 4; r++)
      Crow[(fg*4 + r) * D_ + ns*16 + fr] = f2bf(acc[ns][r] * li[r]);
}

// ---------------- LayerNorm (wave-per-row, bf16 input, no barriers) --------
__global__ __launch_bounds__(256) void ln_kernel(
    const u16* __restrict__ Tmp, const float* __restrict__ g,
    const float* __restrict__ bta, float* __restrict__ out) {
  int wave = threadIdx.x >> 6, lane = threadIdx.x & 63;
  int row = blockIdx.x * 4 + wave;
  const uint2* x2 = (const uint2*)(Tmp + (size_t)row * D_);
  const float4* g4 = (const float4*)g;
  const float4* b4 = (const float4*)bta;
  float4* o4 = (float4*)(out + (size_t)row * D_);
  float v[3][4];
  float s = 0.f, s2 = 0.f;
#pragma unroll
  for (int w = 0; w < 3; w++) {
    uint2 raw = x2[lane + w * 64];
    v[w][0] = bf2f((u16)(raw.x & 0xFFFF));
    v[w][1] = bf2f((u16)(raw.x >> 16));
    v[w][2] = bf2f((u16)(raw.y & 0xFFFF));
    v[w][3] = bf2f((u16)(raw.y >> 16));
#pragma unroll
    for (int e = 0; e < 4; e++) { s += v[w][e]; s2 += v[w][e] * v[w][e]; }
  }
#pragma unroll
  for (int m = 1; m < 64; m <<= 1) { s += __shfl_xor(s, m); s2 += __shfl_xor(s2, m); }
  float mean = s * (1.0f / D_);
  float var = s2 * (1.0f / D_) - mean * mean;
  float inv = rsqrtf(var + 1e-12f);
#pragma unroll
  for (int w = 0; w < 3; w++) {
    float4 gg = g4[lane + w * 64];
    float4 bb = b4[lane + w * 64];
    float4 o;
    o.x = (v[w][0] - mean) * inv * gg.x + bb.x;
    o.y = (v[w][1] - mean) * inv * gg.y + bb.y;
    o.z = (v[w][2] - mean) * inv * gg.z + bb.z;
    o.w = (v[w][3] - mean) * inv * gg.w + bb.w;
    o4[lane + w * 64] = o;
  }
}

// ---------------- launch ----------------
extern "C" void kernel_launch(void* const* d_in, const int* in_sizes, int n_in,
                              void* d_out, int out_size, void* d_ws, size_t ws_size,
                              hipStream_t stream) {
  (void)in_sizes; (void)n_in; (void)out_size; (void)ws_size;
  const float* hidden = (const float*)d_in[0];
  const float* mask   = (const float*)d_in[1];
  const float* Wq = (const float*)d_in[2];
  const float* bq = (const float*)d_in[3];
  const float* Wk = (const float*)d_in[4];
  const float* bk = (const float*)d_in[5];
  const float* Wv = (const float*)d_in[6];
  const float* bv = (const float*)d_in[7];
  const float* Wd = (const float*)d_in[8];
  const float* bd = (const float*)d_in[9];
  const float* ln_g = (const float*)d_in[10];
  const float* ln_b = (const float*)d_in[11];
  float* out = (float*)d_out;

  char* ws = (char*)d_ws;
  u16* Xb    = (u16*)(ws);                 // 12,582,912 B
  u16* Wqkv  = (u16*)(ws + 12582912);      //  3,538,944 B
  u16* Wdb   = (u16*)(ws + 16121856);      //  1,179,648 B
  u16* Q     = (u16*)(ws + 17301504);      // 12,582,912 B
  u16* K     = (u16*)(ws + 29884416);      // 12,582,912 B
  u16* Vt    = (u16*)(ws + 42467328);      // 12,582,912 B  [B,H,64,S] layout
  u16* Ctx   = (u16*)(ws + 55050240);      // 12,582,912 B
  u16* Tmp   = (u16*)(ws + 17301504);      // aliases dead Q, 12,582,912 B (bf16)
  // high-water: 67,633,152 B

  convert_all<<<2048, 256, 0, stream>>>(hidden, Wq, Wk, Wv, Wd, Xb, Wqkv, Wdb);
  gemm_qkv<<<1152, 256, 0, stream>>>(Xb, Wqkv, bq, bk, bv, Q, K, Vt);
  attn_kernel<<<1536, 256, 0, stream>>>(Q, K, Vt, mask, Ctx);
  gemm_out<<<768, 256, 0, stream>>>(Ctx, Wdb, bd, hidden, Tmp);
  ln_kernel<<<2048, 256, 0, stream>>>(Tmp, ln_g, ln_b, out);
}

// Round 12
// 120.267 us; speedup vs baseline: 1.0740x; 1.0740x over previous
//
#include <hip/hip_runtime.h>

typedef unsigned short u16;
typedef unsigned int u32;

#define H_ 12
#define DH_ 64
#define D_ 768
#define S_ 1024
#define B_ 8
#define M_TOT 8192   // B_*S_
#define LOG2E 1.44269504089f

using f32x4  = __attribute__((ext_vector_type(4))) float;
using bf16x8 = __attribute__((ext_vector_type(8))) short;

__device__ inline u16 f2bf(float f) {
  union { float f; u32 u; } v; v.f = f;
  u32 r = v.u + 0x7FFFu + ((v.u >> 16) & 1u);
  return (u16)(r >> 16);
}

__device__ inline float bf2f(u16 b) {
  union { u32 u; float f; } v; v.u = ((u32)b) << 16;
  return v.f;
}

__device__ inline void gload_lds16(const u16* g, u16* l) {
  __builtin_amdgcn_global_load_lds((const __attribute__((address_space(1))) void*)g,
                                   (__attribute__((address_space(3))) void*)l, 16, 0, 0);
}

// ---------------- conversion: f32 -> bf16 (vectorized) ----------------
__global__ void convert_all(const float* __restrict__ X,
                            const float* __restrict__ Wq, const float* __restrict__ Wk,
                            const float* __restrict__ Wv, const float* __restrict__ Wd,
                            u16* __restrict__ Xb, u16* __restrict__ Wqkv, u16* __restrict__ Wdb) {
  int stride = gridDim.x * blockDim.x;
  int tid = blockIdx.x * blockDim.x + threadIdx.x;
  const int NX4 = M_TOT * D_ / 4;
  const int NW4 = D_ * D_ / 4;
  const int NW = D_ * D_;
  for (int i = tid; i < NX4; i += stride) {
    float4 x = ((const float4*)X)[i];
    uint2 p;
    p.x = (u32)f2bf(x.x) | ((u32)f2bf(x.y) << 16);
    p.y = (u32)f2bf(x.z) | ((u32)f2bf(x.w) << 16);
    ((uint2*)Xb)[i] = p;
  }
  for (int i = tid; i < NW4; i += stride) {
    float4 q = ((const float4*)Wq)[i];
    float4 k = ((const float4*)Wk)[i];
    float4 v = ((const float4*)Wv)[i];
    float4 d = ((const float4*)Wd)[i];
    uint2 pq, pk, pv, pd;
    pq.x = (u32)f2bf(q.x) | ((u32)f2bf(q.y) << 16); pq.y = (u32)f2bf(q.z) | ((u32)f2bf(q.w) << 16);
    pk.x = (u32)f2bf(k.x) | ((u32)f2bf(k.y) << 16); pk.y = (u32)f2bf(k.z) | ((u32)f2bf(k.w) << 16);
    pv.x = (u32)f2bf(v.x) | ((u32)f2bf(v.y) << 16); pv.y = (u32)f2bf(v.z) | ((u32)f2bf(v.w) << 16);
    pd.x = (u32)f2bf(d.x) | ((u32)f2bf(d.y) << 16); pd.y = (u32)f2bf(d.z) | ((u32)f2bf(d.w) << 16);
    ((uint2*)Wqkv)[i]            = pq;
    ((uint2*)(Wqkv + NW))[i]     = pk;
    ((uint2*)(Wqkv + 2*NW))[i]   = pv;
    ((uint2*)Wdb)[i]             = pd;
  }
}

// ======================= GEMM 1: QKV projection =======================
#define NT_ 24   // 768/32

__global__ __launch_bounds__(256, 4) void gemm_qkv(
    const u16* __restrict__ A, const u16* __restrict__ Bw,
    const float* __restrict__ bq, const float* __restrict__ bk, const float* __restrict__ bv,
    u16* __restrict__ Q, u16* __restrict__ K, u16* __restrict__ Vt) {
  __shared__ u16 As[2 * 128 * 32];   // 16 KB
  __shared__ u16 Bs[2 * 128 * 32];   // 16 KB
  int tid = threadIdx.x, lane = tid & 63, wave = tid >> 6;
  int wg = blockIdx.x;
  int xcd = wg & 7, li = wg >> 3;          // li 0..143 = 8 m * 18 n
  int m0 = (xcd * 8 + (li & 7)) * 128;
  int n0 = (li >> 3) * 128;
  int wm = (wave >> 1) * 64, wn = (wave & 1) * 64;
  int fr = lane & 15, fg = lane >> 4;
  f32x4 acc[4][4] = {};

  int srow = tid >> 2;                          // 0..63
  int schunk = (lane & 3) ^ ((lane >> 3) & 3);  // pre-swizzled source chunk
  const u16* AgS = A  + (size_t)(m0 + srow) * D_ + schunk * 8;
  const u16* BgS = Bw + (size_t)(n0 + srow) * D_ + schunk * 8;
  u16* Abase = &As[wave * 512];
  u16* Bbase = &Bs[wave * 512];
  int ra = (fg ^ ((fr >> 1) & 3)) * 8;          // swizzled read chunk offset

  gload_lds16(AgS,            Abase);
  gload_lds16(AgS + 64 * D_,  Abase + 2048);
  gload_lds16(BgS,            Bbase);
  gload_lds16(BgS + 64 * D_,  Bbase + 2048);
  __syncthreads();

  for (int t = 0; t < NT_; ++t) {
    int cur = t & 1, nxt = cur ^ 1;
    if (t < NT_ - 1) {
      int k1 = (t + 1) * 32;
      gload_lds16(AgS + k1,           Abase + nxt * 4096);
      gload_lds16(AgS + 64 * D_ + k1, Abase + nxt * 4096 + 2048);
      gload_lds16(BgS + k1,           Bbase + nxt * 4096);
      gload_lds16(BgS + 64 * D_ + k1, Bbase + nxt * 4096 + 2048);
    }
    bf16x8 af[4], bf[4];
#pragma unroll
    for (int i = 0; i < 4; i++) {
      af[i] = *(const bf16x8*)&As[cur * 4096 + (wm + i * 16 + fr) * 32 + ra];
      bf[i] = *(const bf16x8*)&Bs[cur * 4096 + (wn + i * 16 + fr) * 32 + ra];
    }
    __builtin_amdgcn_s_setprio(1);
#pragma unroll
    for (int mi = 0; mi < 4; mi++)
#pragma unroll
      for (int ni = 0; ni < 4; ni++)
        acc[mi][ni] = __builtin_amdgcn_mfma_f32_16x16x32_bf16(af[mi], bf[ni], acc[mi][ni], 0, 0, 0);
    __builtin_amdgcn_s_setprio(0);
    __syncthreads();
  }

  int which = n0 / D_;
  int ncol0 = n0 % D_;
  const float* bias = (which == 0) ? bq : (which == 1) ? bk : bv;
  if (which == 2) {
#pragma unroll
    for (int mi = 0; mi < 4; mi++)
#pragma unroll
      for (int ni = 0; ni < 4; ni++) {
        int col = ncol0 + wn + ni*16 + fr;
        float bb = bias[col];
        int row = m0 + wm + mi*16 + fg*4;
        int bidx = row >> 10, s = row & 1023;
        int hh = col >> 6, dd = col & 63;
        u16 t0 = f2bf(acc[mi][ni][0] + bb);
        u16 t1 = f2bf(acc[mi][ni][1] + bb);
        u16 t2 = f2bf(acc[mi][ni][2] + bb);
        u16 t3 = f2bf(acc[mi][ni][3] + bb);
        uint2 pk2;
        pk2.x = (u32)t0 | ((u32)t1 << 16);
        pk2.y = (u32)t2 | ((u32)t3 << 16);
        *(uint2*)(Vt + ((size_t)((bidx * H_ + hh) * DH_ + dd)) * S_ + s) = pk2;
      }
  } else {
    u16* Out = (which == 0) ? Q : K;
    float scale = (which == 0) ? (0.125f * LOG2E) : 1.0f;
#pragma unroll
    for (int mi = 0; mi < 4; mi++)
#pragma unroll
      for (int ni = 0; ni < 4; ni++) {
        int col = ncol0 + wn + ni*16 + fr;
        float bb = bias[col];
#pragma unroll
        for (int r = 0; r < 4; r++) {
          int row = m0 + wm + mi*16 + fg*4 + r;
          Out[row * D_ + col] = f2bf((acc[mi][ni][r] + bb) * scale);
        }
      }
  }
}

// ============ GEMM 2: output projection + bias + residual (bf16 in/out) ====
__global__ __launch_bounds__(256, 4) void gemm_out(
    const u16* __restrict__ A, const u16* __restrict__ Bw,
    const float* __restrict__ bd, const u16* __restrict__ Xb,
    u16* __restrict__ Tmp) {
  __shared__ u16 As[2 * 64 * 32];    // 8 KB
  __shared__ u16 Bs[2 * 128 * 32];   // 16 KB
  int tid = threadIdx.x, lane = tid & 63, wave = tid >> 6;
  int wg = blockIdx.x;
  int xcd = wg & 7, li = wg >> 3;          // 0..95 = 16 m * 6 n
  int m0 = (xcd * 16 + (li & 15)) * 64;
  int n0 = (li >> 4) * 128;
  int wm = (wave >> 1) * 32, wn = (wave & 1) * 64;
  int fr = lane & 15, fg = lane >> 4;
  f32x4 acc[2][4] = {};

  int srow = tid >> 2;                          // 0..63
  int schunk = (lane & 3) ^ ((lane >> 3) & 3);
  const u16* AgS = A  + (size_t)(m0 + srow) * D_ + schunk * 8;
  const u16* BgS = Bw + (size_t)(n0 + srow) * D_ + schunk * 8;
  u16* Abase = &As[wave * 512];
  u16* Bbase = &Bs[wave * 512];
  int ra = (fg ^ ((fr >> 1) & 3)) * 8;

  gload_lds16(AgS,            Abase);
  gload_lds16(BgS,            Bbase);
  gload_lds16(BgS + 64 * D_,  Bbase + 2048);
  __syncthreads();

  for (int t = 0; t < NT_; ++t) {
    int cur = t & 1, nxt = cur ^ 1;
    if (t < NT_ - 1) {
      int k1 = (t + 1) * 32;
      gload_lds16(AgS + k1,           Abase + nxt * 2048);
      gload_lds16(BgS + k1,           Bbase + nxt * 4096);
      gload_lds16(BgS + 64 * D_ + k1, Bbase + nxt * 4096 + 2048);
    }
    bf16x8 af[2], bf[4];
#pragma unroll
    for (int i = 0; i < 2; i++)
      af[i] = *(const bf16x8*)&As[cur * 2048 + (wm + i * 16 + fr) * 32 + ra];
#pragma unroll
    for (int i = 0; i < 4; i++)
      bf[i] = *(const bf16x8*)&Bs[cur * 4096 + (wn + i * 16 + fr) * 32 + ra];
    __builtin_amdgcn_s_setprio(1);
#pragma unroll
    for (int mi = 0; mi < 2; mi++)
#pragma unroll
      for (int ni = 0; ni < 4; ni++)
        acc[mi][ni] = __builtin_amdgcn_mfma_f32_16x16x32_bf16(af[mi], bf[ni], acc[mi][ni], 0, 0, 0);
    __builtin_amdgcn_s_setprio(0);
    __syncthreads();
  }

#pragma unroll
  for (int mi = 0; mi < 2; mi++)
#pragma unroll
    for (int ni = 0; ni < 4; ni++) {
      int col = n0 + wn + ni*16 + fr;
      float bb = bd[col];
#pragma unroll
      for (int r = 0; r < 4; r++) {
        int row = m0 + wm + mi*16 + fg*4 + r;
        float resid = bf2f(Xb[(size_t)row * D_ + col]);
        Tmp[row * D_ + col] = f2bf(acc[mi][ni][r] + bb + resid);
      }
    }
}

// ---------------- Attention (R9 config: swapped-QK^T, XOR-swizzle, dbuf) ---
// 768 blocks (XCD-swizzled), 4 waves x 32 q-rows. One barrier per tile.
// Mask pre-scaled by log2e staged once in LDS, enters as MFMA C-init.
__global__ __launch_bounds__(256) void attn_kernel(
    const u16* __restrict__ Q, const u16* __restrict__ K, const u16* __restrict__ Vt,
    const float* __restrict__ mask, u16* __restrict__ Ctx) {
  __shared__ u16 Ks[2][64 * 64];   // 16 KB
  __shared__ u16 Vs[2][64 * 64];   // 16 KB
  __shared__ u16 Ps[4][16 * 64];   //  8 KB (per-wave strip)
  __shared__ float Ms[S_];         //  4 KB
  int tid = threadIdx.x, lane = tid & 63, wave = tid >> 6;
  int i = blockIdx.x;
  int xcd = i & 7, slot = i >> 3;
  int bh = xcd * 12 + (slot >> 3);
  int qt = slot & 7;
  int b = bh / H_, h = bh % H_;
  int q0 = qt * 128 + wave * 32;
  int fr = lane & 15, fg = lane >> 4;

  { // stage mask row (pre-scaled by log2e)
    float4 m4 = ((const float4*)(mask + b * S_))[tid];
    m4.x *= LOG2E; m4.y *= LOG2E; m4.z *= LOG2E; m4.w *= LOG2E;
    ((float4*)Ms)[tid] = m4;
  }

  bf16x8 qf[2][2];
#pragma unroll
  for (int s = 0; s < 2; s++) {
    const u16* Qrow = Q + (size_t)(b * S_ + q0 + s*16 + fr) * D_ + h * DH_;
    qf[s][0] = *(const bf16x8*)(Qrow + fg * 8);
    qf[s][1] = *(const bf16x8*)(Qrow + 32 + fg * 8);
  }

  // staging addresses (64 rows x 2 int4 per thread-quad)
  int srow = tid >> 2;
  int scc = (tid & 3) * 16;
  int sw = (srow & 7) << 3;
  int sidx0 = srow * 64 + (scc ^ sw);
  int sidx1 = srow * 64 + ((scc + 8) ^ sw);
  const u16* Kg0 = K  + (size_t)(b * S_ + srow) * D_ + h * DH_ + scc;
  const u16* Vg0 = Vt + (size_t)(bh * DH_ + srow) * S_ + scc;

  // fragment read offsets (swizzled)
  int frw = (fr & 7) << 3;
  int rc0 = (fg * 8) ^ frw;
  int rc1 = (32 + fg * 8) ^ frw;
  int pcw[4];
#pragma unroll
  for (int kb = 0; kb < 4; kb++) pcw[kb] = (kb * 16 + fg * 4) ^ frw;

  f32x4 acc[2][4] = {};
  float l_part[2] = {0.f, 0.f};

  // prologue: stage tile 0 into buf 0
  int4 kr0 = *(const int4*)Kg0;
  int4 kr1 = *(const int4*)(Kg0 + 8);
  int4 vr0 = *(const int4*)Vg0;
  int4 vr1 = *(const int4*)(Vg0 + 8);
  *(int4*)&Ks[0][sidx0] = kr0; *(int4*)&Ks[0][sidx1] = kr1;
  *(int4*)&Vs[0][sidx0] = vr0; *(int4*)&Vs[0][sidx1] = vr1;
  __syncthreads();

  u16* Pw = Ps[wave];

  for (int t = 0; t < 16; ++t) {
    int cur = t & 1;
    int kt = t * 64;
    if (t < 15) {  // issue next-tile loads early; latency hides under compute
      const u16* Kg = Kg0 + (size_t)(kt + 64) * D_;
      const u16* Vg = Vg0 + (kt + 64);
      kr0 = *(const int4*)Kg; kr1 = *(const int4*)(Kg + 8);
      vr0 = *(const int4*)Vg; vr1 = *(const int4*)(Vg + 8);
    }

    f32x4 mv[4];
#pragma unroll
    for (int kb = 0; kb < 4; kb++) {
      float4 m4 = *(const float4*)&Ms[kt + kb*16 + fg*4];
      mv[kb][0] = m4.x; mv[kb][1] = m4.y; mv[kb][2] = m4.z; mv[kb][3] = m4.w;
    }

    bf16x8 kf[4][2];
#pragma unroll
    for (int kb = 0; kb < 4; kb++) {
      int r = kb * 16 + fr;
      kf[kb][0] = *(const bf16x8*)&Ks[cur][r * 64 + rc0];
      kf[kb][1] = *(const bf16x8*)&Ks[cur][r * 64 + rc1];
    }

    bf16x8 pf[2][2];
#pragma unroll
    for (int s = 0; s < 2; s++) {
#pragma unroll
      for (int kb = 0; kb < 4; kb++) {
        f32x4 sv = mv[kb];   // mask folded in as C-init
        sv = __builtin_amdgcn_mfma_f32_16x16x32_bf16(kf[kb][0], qf[s][0], sv, 0, 0, 0);
        sv = __builtin_amdgcn_mfma_f32_16x16x32_bf16(kf[kb][1], qf[s][1], sv, 0, 0, 0);
        float p0 = __builtin_amdgcn_exp2f(sv[0]);
        float p1 = __builtin_amdgcn_exp2f(sv[1]);
        float p2 = __builtin_amdgcn_exp2f(sv[2]);
        float p3 = __builtin_amdgcn_exp2f(sv[3]);
        l_part[s] += (p0 + p1) + (p2 + p3);
        u32 lo, hi;
        asm("v_cvt_pk_bf16_f32 %0, %1, %2" : "=v"(lo) : "v"(p0), "v"(p1));
        asm("v_cvt_pk_bf16_f32 %0, %1, %2" : "=v"(hi) : "v"(p2), "v"(p3));
        uint2 pk2; pk2.x = lo; pk2.y = hi;
        *(uint2*)&Pw[fr * 64 + pcw[kb]] = pk2;
      }
      pf[s][0] = *(const bf16x8*)&Pw[fr * 64 + rc0];
      pf[s][1] = *(const bf16x8*)&Pw[fr * 64 + rc1];
    }

    __builtin_amdgcn_s_setprio(1);
#pragma unroll
    for (int ns = 0; ns < 4; ns++) {
      int r = ns * 16 + fr;
      bf16x8 vf0 = *(const bf16x8*)&Vs[cur][r * 64 + rc0];
      bf16x8 vf1 = *(const bf16x8*)&Vs[cur][r * 64 + rc1];
#pragma unroll
      for (int s = 0; s < 2; s++) {
        acc[s][ns] = __builtin_amdgcn_mfma_f32_16x16x32_bf16(pf[s][0], vf0, acc[s][ns], 0, 0, 0);
        acc[s][ns] = __builtin_amdgcn_mfma_f32_16x16x32_bf16(pf[s][1], vf1, acc[s][ns], 0, 0, 0);
      }
    }
    __builtin_amdgcn_s_setprio(0);

    if (t < 15) {  // write next tile into the other buffer; one barrier/tile
      int nxt = cur ^ 1;
      *(int4*)&Ks[nxt][sidx0] = kr0; *(int4*)&Ks[nxt][sidx1] = kr1;
      *(int4*)&Vs[nxt][sidx0] = vr0; *(int4*)&Vs[nxt][sidx1] = vr1;
      __syncthreads();
    }
  }

  float li[2][4];
#pragma unroll
  for (int s = 0; s < 2; s++) {
    l_part[s] += __shfl_xor(l_part[s], 16);
    l_part[s] += __shfl_xor(l_part[s], 32);
    float inv = 1.0f / l_part[s];
#pragma unroll
    for (int r = 0; r < 4; r++)
      li[s][r] = __shfl(inv, fg*4 + r);
  }
#pragma unroll
  for (int s = 0; s < 2; s++) {
    u16* Crow = Ctx + (size_t)(b * S_ + q0 + s*16) * D_ + h * DH_;
#pragma unroll
    for (int ns = 0; ns < 4; ns++)
#pragma unroll
      for (int r = 0; r < 4; r++)
        Crow[(fg*4 + r) * D_ + ns*16 + fr] = f2bf(acc[s][ns][r] * li[s][r]);
  }
}

// ---------------- LayerNorm (wave-per-row, bf16 input, no barriers) --------
__global__ __launch_bounds__(256) void ln_kernel(
    const u16* __restrict__ Tmp, const float* __restrict__ g,
    const float* __restrict__ bta, float* __restrict__ out) {
  int wave = threadIdx.x >> 6, lane = threadIdx.x & 63;
  int row = blockIdx.x * 4 + wave;
  const uint2* x2 = (const uint2*)(Tmp + (size_t)row * D_);
  const float4* g4 = (const float4*)g;
  const float4* b4 = (const float4*)bta;
  float4* o4 = (float4*)(out + (size_t)row * D_);
  float v[3][4];
  float s = 0.f, s2 = 0.f;
#pragma unroll
  for (int w = 0; w < 3; w++) {
    uint2 raw = x2[lane + w * 64];
    v[w][0] = bf2f((u16)(raw.x & 0xFFFF));
    v[w][1] = bf2f((u16)(raw.x >> 16));
    v[w][2] = bf2f((u16)(raw.y & 0xFFFF));
    v[w][3] = bf2f((u16)(raw.y >> 16));
#pragma unroll
    for (int e = 0; e < 4; e++) { s += v[w][e]; s2 += v[w][e] * v[w][e]; }
  }
#pragma unroll
  for (int m = 1; m < 64; m <<= 1) { s += __shfl_xor(s, m); s2 += __shfl_xor(s2, m); }
  float mean = s * (1.0f / D_);
  float var = s2 * (1.0f / D_) - mean * mean;
  float inv = rsqrtf(var + 1e-12f);
#pragma unroll
  for (int w = 0; w < 3; w++) {
    float4 gg = g4[lane + w * 64];
    float4 bb = b4[lane + w * 64];
    float4 o;
    o.x = (v[w][0] - mean) * inv * gg.x + bb.x;
    o.y = (v[w][1] - mean) * inv * gg.y + bb.y;
    o.z = (v[w][2] - mean) * inv * gg.z + bb.z;
    o.w = (v[w][3] - mean) * inv * gg.w + bb.w;
    o4[lane + w * 64] = o;
  }
}

// ---------------- launch ----------------
extern "C" void kernel_launch(void* const* d_in, const int* in_sizes, int n_in,
                              void* d_out, int out_size, void* d_ws, size_t ws_size,
                              hipStream_t stream) {
  (void)in_sizes; (void)n_in; (void)out_size; (void)ws_size;
  const float* hidden = (const float*)d_in[0];
  const float* mask   = (const float*)d_in[1];
  const float* Wq = (const float*)d_in[2];
  const float* bq = (const float*)d_in[3];
  const float* Wk = (const float*)d_in[4];
  const float* bk = (const float*)d_in[5];
  const float* Wv = (const float*)d_in[6];
  const float* bv = (const float*)d_in[7];
  const float* Wd = (const float*)d_in[8];
  const float* bd = (const float*)d_in[9];
  const float* ln_g = (const float*)d_in[10];
  const float* ln_b = (const float*)d_in[11];
  float* out = (float*)d_out;

  char* ws = (char*)d_ws;
  u16* Xb    = (u16*)(ws);                 // 12,582,912 B (stays live for gemm_out)
  u16* Wqkv  = (u16*)(ws + 12582912);      //  3,538,944 B
  u16* Wdb   = (u16*)(ws + 16121856);      //  1,179,648 B
  u16* Q     = (u16*)(ws + 17301504);      // 12,582,912 B
  u16* K     = (u16*)(ws + 29884416);      // 12,582,912 B
  u16* Vt    = (u16*)(ws + 42467328);      // 12,582,912 B  [B,H,64,S] layout
  u16* Ctx   = (u16*)(ws + 55050240);      // 12,582,912 B
  u16* Tmp   = (u16*)(ws + 17301504);      // aliases dead Q, 12,582,912 B (bf16)
  // high-water: 67,633,152 B

  convert_all<<<2048, 256, 0, stream>>>(hidden, Wq, Wk, Wv, Wd, Xb, Wqkv, Wdb);
  gemm_qkv<<<1152, 256, 0, stream>>>(Xb, Wqkv, bq, bk, bv, Q, K, Vt);
  attn_kernel<<<768, 256, 0, stream>>>(Q, K, Vt, mask, Ctx);
  gemm_out<<<768, 256, 0, stream>>>(Ctx, Wdb, bd, Xb, Tmp);
  ln_kernel<<<2048, 256, 0, stream>>>(Tmp, ln_g, ln_b, out);
}